// Round 2
// baseline (500.846 us; speedup 1.0000x reference)
//
#include <hip/hip_runtime.h>

// LocallyConnected2D: B=16, H=W=64, CIN=32, 3x3 valid, per-location weights,
// F=64, OR=OC=62. One block per p; 16 batches' patches staged in LDS; weight
// stream (283 MB, read once) from global.
//
// R1: R0 was latency-bound (VGPR=28, both pipes <10% busy) — each iteration
// exposed full memory latency. This version register-double-buffers 8 k-rows
// (8x float4 weights + 2x float4 patch) so ~8 loads stay in flight per wave.

#define NB 16
#define Hh 64
#define Ww 64
#define CIN 32
#define F 64
#define OR 62
#define OC 62
#define KK 288      // 3*3*32
#define PADK 292    // +4 dwords: 16B-aligned rows (292*4=73*16), breaks bank aliasing
#define KSTEP 8

__device__ __forceinline__ void fma4(float4& acc, float s, const float4 w) {
    acc.x = fmaf(s, w.x, acc.x);
    acc.y = fmaf(s, w.y, acc.y);
    acc.z = fmaf(s, w.z, acc.z);
    acc.w = fmaf(s, w.w, acc.w);
}

__global__ __launch_bounds__(256)
void lc2d_kernel(const float* __restrict__ x,
                 const float* __restrict__ kern,
                 const float* __restrict__ bias,
                 float* __restrict__ out) {
    __shared__ float patch[NB * PADK];   // 18688 B

    const int p   = blockIdx.x;
    const int orr = p / OC;
    const int occ = p - orr * OC;
    const int tid = threadIdx.x;

    // ---- stage patches: 16 batches x 288 k (kh,kw,cin order), float4 loads ----
    for (int idx = tid; idx < (NB * KK) / 4; idx += 256) {
        const int e = idx << 2;
        const int b = e / KK;
        const int k = e - b * KK;
        const int i = k / 96;
        const int rem = k - i * 96;
        const int j = rem >> 5;
        const int c = rem & 31;
        const float4 v = *reinterpret_cast<const float4*>(
            x + (((b * Hh + orr + i) * Ww) + (occ + j)) * CIN + c);
        *reinterpret_cast<float4*>(&patch[b * PADK + k]) = v;
    }
    __syncthreads();

    // ---- compute: thread = (b = tid/16, f0 = 4*(tid%16)) -> 4 outputs ----
    const int fgrp = tid & 15;
    const int b    = tid >> 4;
    const int f0   = fgrp << 2;

    float4 acc = *reinterpret_cast<const float4*>(bias + p * F + f0);

    const float* __restrict__ wp = kern + (size_t)p * (KK * F) + f0;
    const float* __restrict__ pp = &patch[b * PADK];

    // ---- register double-buffered pipeline over groups of KSTEP k-rows ----
    float4 w[KSTEP], wn[KSTEP];
    float4 pk0, pk1, pkn0, pkn1;

#pragma unroll
    for (int u = 0; u < KSTEP; ++u)
        w[u] = *reinterpret_cast<const float4*>(wp + u * F);
    pk0 = *reinterpret_cast<const float4*>(pp + 0);
    pk1 = *reinterpret_cast<const float4*>(pp + 4);

    for (int k0 = 0; k0 < KK - KSTEP; k0 += KSTEP) {
        const int kn = k0 + KSTEP;
        // prefetch next group (independent of current compute)
#pragma unroll
        for (int u = 0; u < KSTEP; ++u)
            wn[u] = *reinterpret_cast<const float4*>(wp + (kn + u) * F);
        pkn0 = *reinterpret_cast<const float4*>(pp + kn + 0);
        pkn1 = *reinterpret_cast<const float4*>(pp + kn + 4);

        // compute current group: 32 FMAs
        fma4(acc, pk0.x, w[0]);
        fma4(acc, pk0.y, w[1]);
        fma4(acc, pk0.z, w[2]);
        fma4(acc, pk0.w, w[3]);
        fma4(acc, pk1.x, w[4]);
        fma4(acc, pk1.y, w[5]);
        fma4(acc, pk1.z, w[6]);
        fma4(acc, pk1.w, w[7]);

#pragma unroll
        for (int u = 0; u < KSTEP; ++u) w[u] = wn[u];
        pk0 = pkn0;
        pk1 = pkn1;
    }

    // epilogue: last group
    fma4(acc, pk0.x, w[0]);
    fma4(acc, pk0.y, w[1]);
    fma4(acc, pk0.z, w[2]);
    fma4(acc, pk0.w, w[3]);
    fma4(acc, pk1.x, w[4]);
    fma4(acc, pk1.y, w[5]);
    fma4(acc, pk1.z, w[6]);
    fma4(acc, pk1.w, w[7]);

    float* op = out + (((size_t)b * OR + orr) * OC + occ) * F + f0;
    *reinterpret_cast<float4*>(op) = acc;
}

extern "C" void kernel_launch(void* const* d_in, const int* in_sizes, int n_in,
                              void* d_out, int out_size, void* d_ws, size_t ws_size,
                              hipStream_t stream) {
    const float* x    = (const float*)d_in[0];
    const float* kern = (const float*)d_in[1];
    const float* bias = (const float*)d_in[2];
    float* out = (float*)d_out;
    lc2d_kernel<<<dim3(OR * OC), dim3(256), 0, stream>>>(x, kern, bias, out);
}

// Round 3
// 418.990 us; speedup vs baseline: 1.1954x; 1.1954x over previous
//
#include <hip/hip_runtime.h>

// LocallyConnected2D: B=16, H=W=64, CIN=32, 3x3 valid, F=64, OR=OC=62.
// R2: R0/R1 were L1-transport bound: weight loads were 4x lane-redundant and
// 4x wave-redundant (16 line-requests per instr, 256B distinct). Now each
// weight load-instr covers 1 KB distinct (lane l -> k-row l/16, f 4*(l%16)),
// each wave owns a disjoint 72-row k-slice, acc[16 b][4 f] in registers.
// Patches transposed into LDS patchT[k][b] (row stride 20 -> conflict-free).
// Reduction: 64 shfl_xor intra-wave + LDS tile cross-wave.

#define NB 16
#define CIN 32
#define F 64
#define OR 62
#define OC 62
#define KK 288
#define PADT 20       // patchT row stride (floats): 16B-aligned, conflict-free
#define KPW 72        // k-rows per wave

__device__ __forceinline__ void fma4(float4& acc, float s, const float4 w) {
    acc.x = fmaf(s, w.x, acc.x);
    acc.y = fmaf(s, w.y, acc.y);
    acc.z = fmaf(s, w.z, acc.z);
    acc.w = fmaf(s, w.w, acc.w);
}

__global__ __launch_bounds__(256, 4)
void lc2d_kernel(const float* __restrict__ x,
                 const float* __restrict__ kern,
                 const float* __restrict__ bias,
                 float* __restrict__ out) {
    __shared__ __align__(16) float patchT[KK * PADT];   // 23040 B; reused as redtile

    const int p    = blockIdx.x;
    const int orr  = p / OC;
    const int occ  = p - orr * OC;
    const int tid  = threadIdx.x;
    const int lane = tid & 63;
    const int wv   = tid >> 6;      // wave 0..3
    const int q    = lane >> 4;     // quarter 0..3 -> k-row within 4-row group
    const int fq   = lane & 15;     // f4 slot

    // ---- stage patchT[k][b]; b-major lanes so ds_write banks are 2-way-free ----
    for (int idx = tid; idx < NB * KK / 4; idx += 256) {
        const int b = idx & 15;
        const int k = (idx >> 4) << 2;       // 4-aligned (c 4-aligned too)
        const int i = k / 96;
        const int r = k - i * 96;
        const int j = r >> 5;
        const int c = r & 31;
        const float4 v = *reinterpret_cast<const float4*>(
            x + (((b * 64 + orr + i) * 64) + (occ + j)) * CIN + c);
        patchT[(k + 0) * PADT + b] = v.x;
        patchT[(k + 1) * PADT + b] = v.y;
        patchT[(k + 2) * PADT + b] = v.z;
        patchT[(k + 3) * PADT + b] = v.w;
    }
    __syncthreads();

    // ---- main loop: 18 iters, 1 KB distinct weight load per wave-instr ----
    float4 acc[16];
#pragma unroll
    for (int u = 0; u < 16; ++u) acc[u] = make_float4(0.f, 0.f, 0.f, 0.f);

    const float* __restrict__ wp =
        kern + (size_t)p * (KK * F) + (KPW * wv + q) * F + 4 * fq;
    const float* __restrict__ ptbase = &patchT[(KPW * wv + q) * PADT];

    float4 wreg = *reinterpret_cast<const float4*>(wp);
#pragma unroll 2
    for (int t = 0; t < 18; ++t) {
        const float4 wcur = wreg;
        if (t < 17)
            wreg = *reinterpret_cast<const float4*>(wp + (t + 1) * (4 * F));
        const float* pt = ptbase + t * (4 * PADT);
        const float4 p0 = *reinterpret_cast<const float4*>(pt + 0);
        const float4 p1 = *reinterpret_cast<const float4*>(pt + 4);
        const float4 p2 = *reinterpret_cast<const float4*>(pt + 8);
        const float4 p3 = *reinterpret_cast<const float4*>(pt + 12);
        fma4(acc[0],  p0.x, wcur); fma4(acc[1],  p0.y, wcur);
        fma4(acc[2],  p0.z, wcur); fma4(acc[3],  p0.w, wcur);
        fma4(acc[4],  p1.x, wcur); fma4(acc[5],  p1.y, wcur);
        fma4(acc[6],  p1.z, wcur); fma4(acc[7],  p1.w, wcur);
        fma4(acc[8],  p2.x, wcur); fma4(acc[9],  p2.y, wcur);
        fma4(acc[10], p2.z, wcur); fma4(acc[11], p2.w, wcur);
        fma4(acc[12], p3.x, wcur); fma4(acc[13], p3.y, wcur);
        fma4(acc[14], p3.z, wcur); fma4(acc[15], p3.w, wcur);
    }

    // ---- intra-wave reduction across quarters (k mod 4 partials) ----
    // step 1 (xor 32): exchange the b-half the partner keeps.
    const bool hi = (q >= 2);       // quarters 2,3 keep b8..15
    float4 acck[8];
#pragma unroll
    for (int s = 0; s < 8; ++s) {
        float4 send = hi ? acc[s] : acc[s + 8];
        float4 recv;
        recv.x = __shfl_xor(send.x, 32);
        recv.y = __shfl_xor(send.y, 32);
        recv.z = __shfl_xor(send.z, 32);
        recv.w = __shfl_xor(send.w, 32);
        const float4 mine = hi ? acc[s + 8] : acc[s];
        acck[s] = make_float4(mine.x + recv.x, mine.y + recv.y,
                              mine.z + recv.z, mine.w + recv.w);
    }
    // step 2 (xor 16): sum the remaining two k-partials.
#pragma unroll
    for (int s = 0; s < 8; ++s) {
        acck[s].x += __shfl_xor(acck[s].x, 16);
        acck[s].y += __shfl_xor(acck[s].y, 16);
        acck[s].z += __shfl_xor(acck[s].z, 16);
        acck[s].w += __shfl_xor(acck[s].w, 16);
    }

    // ---- cross-wave reduction via LDS (reuse patchT) ----
    __syncthreads();   // all patchT reads done before overwrite
    {
        const int sbase = (q & 1) * 4;           // which kept slots this quarter writes
        float* red = patchT + wv * 1024 + (4 * q) * F + 4 * fq;  // b = 4q+u
#pragma unroll
        for (int u = 0; u < 4; ++u)
            *reinterpret_cast<float4*>(red + u * F) = acck[sbase + u];
    }
    __syncthreads();

    // ---- epilogue: thread t -> (b = t/16, f4 = t%16); sum 4 waves + bias ----
    {
        const int fb = tid >> 4;
        const int ff = tid & 15;
        const float* r0 = patchT + fb * F + 4 * ff;
        float4 s0 = *reinterpret_cast<const float4*>(r0 + 0 * 1024);
        float4 s1 = *reinterpret_cast<const float4*>(r0 + 1 * 1024);
        float4 s2 = *reinterpret_cast<const float4*>(r0 + 2 * 1024);
        float4 s3 = *reinterpret_cast<const float4*>(r0 + 3 * 1024);
        const float4 bv = *reinterpret_cast<const float4*>(bias + p * F + 4 * ff);
        float4 o;
        o.x = s0.x + s1.x + s2.x + s3.x + bv.x;
        o.y = s0.y + s1.y + s2.y + s3.y + bv.y;
        o.z = s0.z + s1.z + s2.z + s3.z + bv.z;
        o.w = s0.w + s1.w + s2.w + s3.w + bv.w;
        float* op = out + ((size_t)fb * (OR * OC) + p) * F + 4 * ff;
        *reinterpret_cast<float4*>(op) = o;
    }
}

extern "C" void kernel_launch(void* const* d_in, const int* in_sizes, int n_in,
                              void* d_out, int out_size, void* d_ws, size_t ws_size,
                              hipStream_t stream) {
    const float* x    = (const float*)d_in[0];
    const float* kern = (const float*)d_in[1];
    const float* bias = (const float*)d_in[2];
    float* out = (float*)d_out;
    lc2d_kernel<<<dim3(OR * OC), dim3(256), 0, stream>>>(x, kern, bias, out);
}